// Round 1
// baseline (269.291 us; speedup 1.0000x reference)
//
#include <hip/hip_runtime.h>

// hardwiredAttention: out[b,i,h] = sum_j w[b,i,j] * h_t[j,b,h]
//   w = m_i*m_j*relu(domain[cog,r]-d) / max(w)
// Strategy: fused gather+relu+mask -> bf16 MFMA GEMM (unnormalized) + global
// atomicMax; separate scale kernel applies m_i/gmax. h_t pre-transposed to
// T[b][h][j] bf16 so B-fragments are single 16B loads.

#define B_   64
#define N_   512
#define H_   128
#define NCOG 72
#define NRB  72

typedef __bf16 bf16x8 __attribute__((ext_vector_type(8)));
typedef float  f32x4  __attribute__((ext_vector_type(4)));

// ---------- h_t[j][b][h] fp32 -> T[b][h][j] bf16 ----------
__global__ __launch_bounds__(256) void k_transpose(const float* __restrict__ ht,
                                                   __bf16* __restrict__ T) {
    __shared__ __bf16 tile[32][136];   // +8 bf16 pad to spread banks
    const int jt = blockIdx.x * 32;
    const int b  = blockIdx.y;
    const int t  = threadIdx.x;
    {   // load 32 j-rows x 128 h, coalesced on h
        const int jj = t >> 3;            // 0..31
        const int h0 = (t & 7) << 4;      // 0,16,..,112
        const float* src = ht + ((size_t)(jt + jj) * B_ + b) * H_ + h0;
        float4 v0 = *(const float4*)(src + 0);
        float4 v1 = *(const float4*)(src + 4);
        float4 v2 = *(const float4*)(src + 8);
        float4 v3 = *(const float4*)(src + 12);
        __bf16* dst = &tile[jj][h0];
        dst[0]=(__bf16)v0.x; dst[1]=(__bf16)v0.y; dst[2]=(__bf16)v0.z; dst[3]=(__bf16)v0.w;
        dst[4]=(__bf16)v1.x; dst[5]=(__bf16)v1.y; dst[6]=(__bf16)v1.z; dst[7]=(__bf16)v1.w;
        dst[8]=(__bf16)v2.x; dst[9]=(__bf16)v2.y; dst[10]=(__bf16)v2.z; dst[11]=(__bf16)v2.w;
        dst[12]=(__bf16)v3.x; dst[13]=(__bf16)v3.y; dst[14]=(__bf16)v3.z; dst[15]=(__bf16)v3.w;
    }
    __syncthreads();
    {   // store: each thread one h, 16 consecutive j (32B contiguous)
        const int h  = t >> 1;            // 0..127
        const int j0 = (t & 1) << 4;      // 0 or 16
        union { bf16x8 v[2]; __bf16 e[16]; } ob;
        #pragma unroll
        for (int q = 0; q < 16; ++q) ob.e[q] = tile[j0 + q][h];
        __bf16* dst = T + ((size_t)b * H_ + h) * N_ + jt + j0;
        *(bf16x8*)(dst + 0) = ob.v[0];
        *(bf16x8*)(dst + 8) = ob.v[1];
    }
}

// ---------- fused gather/relu/mask + MFMA GEMM (unnormalized) + global max ----
__global__ __launch_bounds__(256) void k_main(const int* __restrict__ cog,
                                              const int* __restrict__ rmat,
                                              const float* __restrict__ dmat,
                                              const float* __restrict__ mask,
                                              const float* __restrict__ domain,
                                              const __bf16* __restrict__ T,
                                              float* __restrict__ out,
                                              unsigned int* __restrict__ gmax) {
    __shared__ float sdom[NCOG * NRB];   // 20736 B
    __shared__ float smask[N_];          // 2048 B
    const int b  = blockIdx.y;
    const int i0 = blockIdx.x * 64;
    const int t  = threadIdx.x;
    for (int k = t; k < NCOG * NRB; k += 256) sdom[k] = domain[k];
    for (int k = t; k < N_; k += 256) smask[k] = mask[b * N_ + k];
    __syncthreads();

    const int wave = t >> 6;
    const int lane = t & 63;
    const int quad = lane >> 4;
    const int lrow = lane & 15;
    const int irow = i0 + wave * 16 + lrow;            // A row (lane's W row)
    const size_t rowbase = ((size_t)b * N_ + irow) * N_;
    const float mi = smask[irow];
    const __bf16* Tb = T + (size_t)b * H_ * N_ + (size_t)lrow * N_;

    f32x4 acc[8];
    #pragma unroll
    for (int i = 0; i < 8; ++i) acc[i] = (f32x4)0.0f;
    float wmax = 0.0f;

    for (int kk = 0; kk < N_; kk += 32) {
        const int jb = kk + quad * 8;                  // lane's 8 j's
        union { int4 v[2]; int e[8]; } ci, ri;
        union { float4 v[2]; float e[8]; } di, mj8;
        ci.v[0] = *(const int4*)(cog + rowbase + jb);
        ci.v[1] = *(const int4*)(cog + rowbase + jb + 4);
        ri.v[0] = *(const int4*)(rmat + rowbase + jb);
        ri.v[1] = *(const int4*)(rmat + rowbase + jb + 4);
        di.v[0] = *(const float4*)(dmat + rowbase + jb);
        di.v[1] = *(const float4*)(dmat + rowbase + jb + 4);
        mj8.v[0] = *(const float4*)(&smask[jb]);
        mj8.v[1] = *(const float4*)(&smask[jb + 4]);

        union { bf16x8 v8; __bf16 e[8]; } af;
        #pragma unroll
        for (int q = 0; q < 8; ++q) {
            float val = sdom[ci.e[q] * NRB + ri.e[q]] - di.e[q];  // gather - dist
            val = fmaxf(val, 0.0f) * mj8.e[q];                    // relu * m_j
            wmax = fmaxf(wmax, val);                              // (m_i applied later)
            af.e[q] = (__bf16)val;
        }

        const __bf16* tb = Tb + kk + quad * 8;
        #pragma unroll
        for (int nt = 0; nt < 8; ++nt) {
            bf16x8 bf = *(const bf16x8*)(tb + (size_t)nt * 16 * N_);
            acc[nt] = __builtin_amdgcn_mfma_f32_16x16x32_bf16(af.v8, bf, acc[nt], 0, 0, 0);
        }
    }
    wmax *= mi;   // mask_i is per-lane-constant; fold once

    // wave reduce max, one atomic per wave (floats >=0: uint compare == float compare)
    #pragma unroll
    for (int off = 32; off > 0; off >>= 1)
        wmax = fmaxf(wmax, __shfl_down(wmax, off));
    if (lane == 0) atomicMax(gmax, __float_as_uint(wmax));

    // write unnormalized output; D layout: col=lane&15, row=quad*4+reg
    const int orow0 = i0 + wave * 16 + quad * 4;
    #pragma unroll
    for (int nt = 0; nt < 8; ++nt) {
        #pragma unroll
        for (int r = 0; r < 4; ++r)
            out[((size_t)b * N_ + orow0 + r) * H_ + nt * 16 + lrow] = acc[nt][r];
    }
}

// ---------- scale by m_i / gmax ----------
__global__ __launch_bounds__(256) void k_scale(float* __restrict__ out,
                                               const float* __restrict__ mask,
                                               const unsigned int* __restrict__ gmax) {
    const float inv = 1.0f / __uint_as_float(*gmax);
    const int idx = blockIdx.x * 256 + threadIdx.x;     // 1,048,576 float4s
    const float m = mask[idx >> 5] * inv;               // 32 float4 per (b,i) row
    float4* p = (float4*)out;
    float4 v = p[idx];
    v.x *= m; v.y *= m; v.z *= m; v.w *= m;
    p[idx] = v;
}

extern "C" void kernel_launch(void* const* d_in, const int* in_sizes, int n_in,
                              void* d_out, int out_size, void* d_ws, size_t ws_size,
                              hipStream_t stream) {
    const float* ht     = (const float*)d_in[0];   // (N,B,H) f32
    const int*   rmat   = (const int*)  d_in[1];   // (B,N,N) i32
    const float* dmat   = (const float*)d_in[2];   // (B,N,N) f32
    const float* mask   = (const float*)d_in[3];   // (B,N)   f32
    const int*   cog    = (const int*)  d_in[4];   // (B,N,N) i32
    const float* domain = (const float*)d_in[5];   // (72,72) f32
    float* out = (float*)d_out;

    unsigned int* gmax = (unsigned int*)d_ws;
    __bf16* T = (__bf16*)((char*)d_ws + 256);      // 8 MiB bf16 transpose buffer

    hipMemsetAsync(d_ws, 0, 256, stream);          // gmax = 0.0f
    k_transpose<<<dim3(16, 64), 256, 0, stream>>>(ht, T);
    k_main<<<dim3(8, 64), 256, 0, stream>>>(cog, rmat, dmat, mask, domain, T, out, gmax);
    k_scale<<<4096, 256, 0, stream>>>(out, mask, gmax);
}

// Round 2
// 251.163 us; speedup vs baseline: 1.0722x; 1.0722x over previous
//
#include <hip/hip_runtime.h>

// hardwiredAttention: out[b,i,h] = sum_j w[b,i,j] * h_t[j,b,h]
//   w = m_i*m_j*relu(domain[cog,r]-d) / max(w)
// R2: in-block split-K (8 waves: K-halves) + register prefetch pipeline.
// Unnormalized GEMM + global atomicMax; scale kernel applies m_i/gmax.

#define B_   64
#define N_   512
#define H_   128
#define NCOG 72
#define NRB  72

typedef __bf16 bf16x8 __attribute__((ext_vector_type(8)));
typedef float  f32x4  __attribute__((ext_vector_type(4)));

// ---------- h_t[j][b][h] fp32 -> T[b][h][j] bf16 ----------
__global__ __launch_bounds__(256) void k_transpose(const float* __restrict__ ht,
                                                   __bf16* __restrict__ T) {
    __shared__ __bf16 tile[32][136];   // +8 bf16 pad to spread banks
    const int jt = blockIdx.x * 32;
    const int b  = blockIdx.y;
    const int t  = threadIdx.x;
    {   // load 32 j-rows x 128 h, coalesced on h
        const int jj = t >> 3;            // 0..31
        const int h0 = (t & 7) << 4;      // 0,16,..,112
        const float* src = ht + ((size_t)(jt + jj) * B_ + b) * H_ + h0;
        float4 v0 = *(const float4*)(src + 0);
        float4 v1 = *(const float4*)(src + 4);
        float4 v2 = *(const float4*)(src + 8);
        float4 v3 = *(const float4*)(src + 12);
        __bf16* dst = &tile[jj][h0];
        dst[0]=(__bf16)v0.x; dst[1]=(__bf16)v0.y; dst[2]=(__bf16)v0.z; dst[3]=(__bf16)v0.w;
        dst[4]=(__bf16)v1.x; dst[5]=(__bf16)v1.y; dst[6]=(__bf16)v1.z; dst[7]=(__bf16)v1.w;
        dst[8]=(__bf16)v2.x; dst[9]=(__bf16)v2.y; dst[10]=(__bf16)v2.z; dst[11]=(__bf16)v2.w;
        dst[12]=(__bf16)v3.x; dst[13]=(__bf16)v3.y; dst[14]=(__bf16)v3.z; dst[15]=(__bf16)v3.w;
    }
    __syncthreads();
    {   // store: each thread one h, 16 consecutive j (32B contiguous)
        const int h  = t >> 1;            // 0..127
        const int j0 = (t & 1) << 4;      // 0 or 16
        union { bf16x8 v[2]; __bf16 e[16]; } ob;
        #pragma unroll
        for (int q = 0; q < 16; ++q) ob.e[q] = tile[j0 + q][h];
        __bf16* dst = T + ((size_t)b * H_ + h) * N_ + jt + j0;
        *(bf16x8*)(dst + 0) = ob.v[0];
        *(bf16x8*)(dst + 8) = ob.v[1];
    }
}

struct Batch { int4 c0, c1, r0, r1; float4 d0, d1; };

// ---------- fused gather/relu/mask + MFMA GEMM (unnormalized) + global max ----
__global__ __launch_bounds__(512, 4) void k_main(const int* __restrict__ cog,
                                                 const int* __restrict__ rmat,
                                                 const float* __restrict__ dmat,
                                                 const float* __restrict__ mask,
                                                 const float* __restrict__ domain,
                                                 const __bf16* __restrict__ T,
                                                 float* __restrict__ out,
                                                 unsigned int* __restrict__ gmax) {
    __shared__ float sdom[NCOG * NRB];        // 20736 B
    __shared__ float smask[N_];               // 2048 B
    __shared__ float sred[4][16][132];        // 33792 B (pad 132: 2-way max -> free)
    __shared__ float swmax[8];
    const int b  = blockIdx.y;
    const int i0 = blockIdx.x * 64;
    const int t  = threadIdx.x;
    for (int k = t; k < NCOG * NRB; k += 512) sdom[k] = domain[k];
    for (int k = t; k < N_; k += 512) smask[k] = mask[b * N_ + k];
    __syncthreads();

    const int wave = t >> 6;
    const int lane = t & 63;
    const int quad = lane >> 4;
    const int lrow = lane & 15;
    const int wi   = wave & 3;                 // row-group 0..3
    const int kh   = wave >> 2;                // K-half 0/1
    const int irow = i0 + wi * 16 + lrow;      // A row (lane's W row)
    const size_t rowbase = ((size_t)b * N_ + irow) * N_;
    const int kbeg = kh * 256;

    const int*   cp = cog  + rowbase + kbeg + quad * 8;
    const int*   rp = rmat + rowbase + kbeg + quad * 8;
    const float* dp = dmat + rowbase + kbeg + quad * 8;
    const __bf16* Tb = T + (size_t)b * H_ * N_ + (size_t)lrow * N_ + kbeg + quad * 8;

    f32x4 acc[8];
    #pragma unroll
    for (int i = 0; i < 8; ++i) acc[i] = (f32x4)0.0f;
    float wmax = 0.0f;

    Batch cur, nxt;
    cur.c0 = *(const int4*)(cp);     cur.c1 = *(const int4*)(cp + 4);
    cur.r0 = *(const int4*)(rp);     cur.r1 = *(const int4*)(rp + 4);
    cur.d0 = *(const float4*)(dp);   cur.d1 = *(const float4*)(dp + 4);

    #pragma unroll
    for (int s = 0; s < 8; ++s) {                      // 8 K-steps of 32
        const int kk = s * 32;
        // (1) T-fragment loads for current step, issued first so the MFMA
        //     waitcnt does not drain the prefetch batch behind them
        bf16x8 bf[8];
        #pragma unroll
        for (int nt = 0; nt < 8; ++nt)
            bf[nt] = *(const bf16x8*)(Tb + kk + (size_t)nt * 16 * N_);
        // (2) prefetch next step's streaming batch
        if (s < 7) {
            nxt.c0 = *(const int4*)(cp + kk + 32);  nxt.c1 = *(const int4*)(cp + kk + 36);
            nxt.r0 = *(const int4*)(rp + kk + 32);  nxt.r1 = *(const int4*)(rp + kk + 36);
            nxt.d0 = *(const float4*)(dp + kk + 32); nxt.d1 = *(const float4*)(dp + kk + 36);
        }
        // (3) gather + relu + mask_j -> bf16 A-fragment
        union { int4 v[2]; int e[8]; } ci, ri;
        union { float4 v[2]; float e[8]; } di;
        ci.v[0] = cur.c0; ci.v[1] = cur.c1;
        ri.v[0] = cur.r0; ri.v[1] = cur.r1;
        di.v[0] = cur.d0; di.v[1] = cur.d1;
        const int jb = kbeg + kk + quad * 8;
        union { bf16x8 v8; __bf16 e[8]; } af;
        #pragma unroll
        for (int q = 0; q < 8; ++q) {
            float val = sdom[ci.e[q] * NRB + ri.e[q]] - di.e[q];
            val = fmaxf(val, 0.0f) * smask[jb + q];
            wmax = fmaxf(wmax, val);
            af.e[q] = (__bf16)val;
        }
        // (4) MFMAs
        #pragma unroll
        for (int nt = 0; nt < 8; ++nt)
            acc[nt] = __builtin_amdgcn_mfma_f32_16x16x32_bf16(af.v8, bf[nt], acc[nt], 0, 0, 0);
        cur = nxt;
    }
    wmax *= smask[irow];   // fold mask_i into the max once

    // wave reduce max -> one slot per wave
    #pragma unroll
    for (int off = 32; off > 0; off >>= 1)
        wmax = fmaxf(wmax, __shfl_down(wmax, off));
    if (lane == 0) swmax[wave] = wmax;

    // upper K-half waves park partials in LDS
    if (kh == 1) {
        #pragma unroll
        for (int nt = 0; nt < 8; ++nt)
            #pragma unroll
            for (int r = 0; r < 4; ++r)
                sred[wi][quad * 4 + r][nt * 16 + lrow] = acc[nt][r];
    }
    __syncthreads();

    if (t == 0) {
        float m = swmax[0];
        #pragma unroll
        for (int w = 1; w < 8; ++w) m = fmaxf(m, swmax[w]);
        atomicMax(gmax, __float_as_uint(m));   // floats >= 0: uint cmp == float cmp
    }

    if (kh == 0) {
        const int orow0 = i0 + wi * 16 + quad * 4;
        #pragma unroll
        for (int nt = 0; nt < 8; ++nt) {
            #pragma unroll
            for (int r = 0; r < 4; ++r) {
                float v = acc[nt][r] + sred[wi][quad * 4 + r][nt * 16 + lrow];
                out[((size_t)b * N_ + orow0 + r) * H_ + nt * 16 + lrow] = v;
            }
        }
    }
}

// ---------- scale by m_i / gmax ----------
__global__ __launch_bounds__(256) void k_scale(float* __restrict__ out,
                                               const float* __restrict__ mask,
                                               const unsigned int* __restrict__ gmax) {
    const float inv = 1.0f / __uint_as_float(*gmax);
    const int idx = blockIdx.x * 256 + threadIdx.x;     // 1,048,576 float4s
    const float m = mask[idx >> 5] * inv;               // 32 float4 per (b,i) row
    float4* p = (float4*)out;
    float4 v = p[idx];
    v.x *= m; v.y *= m; v.z *= m; v.w *= m;
    p[idx] = v;
}

extern "C" void kernel_launch(void* const* d_in, const int* in_sizes, int n_in,
                              void* d_out, int out_size, void* d_ws, size_t ws_size,
                              hipStream_t stream) {
    const float* ht     = (const float*)d_in[0];   // (N,B,H) f32
    const int*   rmat   = (const int*)  d_in[1];   // (B,N,N) i32
    const float* dmat   = (const float*)d_in[2];   // (B,N,N) f32
    const float* mask   = (const float*)d_in[3];   // (B,N)   f32
    const int*   cog    = (const int*)  d_in[4];   // (B,N,N) i32
    const float* domain = (const float*)d_in[5];   // (72,72) f32
    float* out = (float*)d_out;

    unsigned int* gmax = (unsigned int*)d_ws;
    __bf16* T = (__bf16*)((char*)d_ws + 256);      // 8 MiB bf16 transpose buffer

    hipMemsetAsync(d_ws, 0, 256, stream);          // gmax = 0.0f
    k_transpose<<<dim3(16, 64), 256, 0, stream>>>(ht, T);
    k_main<<<dim3(8, 64), 512, 0, stream>>>(cog, rmat, dmat, mask, domain, T, out, gmax);
    k_scale<<<4096, 256, 0, stream>>>(out, mask, gmax);
}

// Round 3
// 239.892 us; speedup vs baseline: 1.1226x; 1.0470x over previous
//
#include <hip/hip_runtime.h>

// hardwiredAttention: out[b,i,h] = sum_j w[b,i,j] * h_t[j,b,h]
//   w = m_i*m_j*relu(domain[cog,r]-d) / max(w)
// R3: producer/consumer wave specialization. Producer waves (4-7) stage
// cog/r/d K-tiles to double-buffered LDS via global_load_lds (bulk in-flight
// bytes, no VGPR cost). Consumer waves (0-3) read tiles via ds_read_b128
// (XOR-swizzled, conflict-free) and run gather+relu+mask -> bf16 MFMA.
// No split-K (full K per wave) -> no reduction LDS. XCD swizzle for T L2 hits.

#define B_   64
#define N_   512
#define H_   128
#define NCOG 72
#define NRB  72

typedef __bf16 bf16x8 __attribute__((ext_vector_type(8)));
typedef float  f32x4  __attribute__((ext_vector_type(4)));

__device__ __forceinline__ void async_copy16(const void* g, void* l) {
    __builtin_amdgcn_global_load_lds(
        (const __attribute__((address_space(1))) void*)g,
        (__attribute__((address_space(3))) void*)l, 16, 0, 0);
}

// ---------- h_t[j][b][h] fp32 -> T[b][h][j] bf16 ----------
__global__ __launch_bounds__(256) void k_transpose(const float* __restrict__ ht,
                                                   __bf16* __restrict__ T) {
    __shared__ __bf16 tile[32][136];
    const int jt = blockIdx.x * 32;
    const int b  = blockIdx.y;
    const int t  = threadIdx.x;
    {
        const int jj = t >> 3;
        const int h0 = (t & 7) << 4;
        const float* src = ht + ((size_t)(jt + jj) * B_ + b) * H_ + h0;
        float4 v0 = *(const float4*)(src + 0);
        float4 v1 = *(const float4*)(src + 4);
        float4 v2 = *(const float4*)(src + 8);
        float4 v3 = *(const float4*)(src + 12);
        __bf16* dst = &tile[jj][h0];
        dst[0]=(__bf16)v0.x; dst[1]=(__bf16)v0.y; dst[2]=(__bf16)v0.z; dst[3]=(__bf16)v0.w;
        dst[4]=(__bf16)v1.x; dst[5]=(__bf16)v1.y; dst[6]=(__bf16)v1.z; dst[7]=(__bf16)v1.w;
        dst[8]=(__bf16)v2.x; dst[9]=(__bf16)v2.y; dst[10]=(__bf16)v2.z; dst[11]=(__bf16)v2.w;
        dst[12]=(__bf16)v3.x; dst[13]=(__bf16)v3.y; dst[14]=(__bf16)v3.z; dst[15]=(__bf16)v3.w;
    }
    __syncthreads();
    {
        const int h  = t >> 1;
        const int j0 = (t & 1) << 4;
        union { bf16x8 v[2]; __bf16 e[16]; } ob;
        #pragma unroll
        for (int q = 0; q < 16; ++q) ob.e[q] = tile[j0 + q][h];
        __bf16* dst = T + ((size_t)b * H_ + h) * N_ + jt + j0;
        *(bf16x8*)(dst + 0) = ob.v[0];
        *(bf16x8*)(dst + 8) = ob.v[1];
    }
}

// ---------- producer/consumer fused kernel ----------
__global__ __launch_bounds__(512, 4) void k_main(const int* __restrict__ cog,
                                                 const int* __restrict__ rmat,
                                                 const float* __restrict__ dmat,
                                                 const float* __restrict__ mask,
                                                 const float* __restrict__ domain,
                                                 const __bf16* __restrict__ T,
                                                 float* __restrict__ out,
                                                 unsigned int* __restrict__ gmax) {
    __shared__ int   tiles[2 * 3 * 2048];   // [buf][array][64 rows x 32 k] 48 KB
    __shared__ float sdom[NCOG * NRB];      // 20736 B
    __shared__ float smask[N_];             // 2048 B
    __shared__ float swmax[8];

    // XCD swizzle: same-b blocks land on the same XCD (ids differ by 8)
    const int id    = blockIdx.x;
    const int xcd   = id & 7;
    const int i0idx = (id >> 3) & 7;
    const int bhi   = id >> 6;
    const int b     = xcd + 8 * bhi;
    const int i0    = i0idx * 64;

    const int t    = threadIdx.x;
    const int wave = t >> 6;
    const int lane = t & 63;

    for (int k = t; k < NCOG * NRB; k += 512) sdom[k] = domain[k];
    for (int k = t; k < N_; k += 512) smask[k] = mask[b * N_ + k];

    const size_t robase = ((size_t)b * N_ + i0) * N_;   // element offset of tile row 0

    float wmax = 0.0f;

    if (wave >= 4) {
        // ================= producer =================
        const int pw   = wave - 4;                       // 0..3
        const int csw4 = ((lane & 7) ^ (lane >> 3)) * 4; // swizzled chunk (step-invariant)
        const size_t poff = (size_t)(lane >> 3) * N_ + csw4;

        // stage step 0 into buf 0
        #pragma unroll
        for (int q6 = 0; q6 < 6; ++q6) {
            const int q = pw * 6 + q6, a = q >> 3, c8 = q & 7;
            const size_t goff = robase + (size_t)(c8 * 8) * N_ + poff;
            const void* g = (a == 0) ? (const void*)(cog + goff)
                          : (a == 1) ? (const void*)(rmat + goff)
                                     : (const void*)(dmat + goff);
            async_copy16(g, &tiles[a * 2048 + c8 * 256]);
        }
        __syncthreads();
        for (int s = 0; s < 16; ++s) {
            if (s + 1 < 16) {
                const int kk  = (s + 1) * 32;
                const int buf = (s + 1) & 1;
                #pragma unroll
                for (int q6 = 0; q6 < 6; ++q6) {
                    const int q = pw * 6 + q6, a = q >> 3, c8 = q & 7;
                    const size_t goff = robase + (size_t)(c8 * 8) * N_ + kk + poff;
                    const void* g = (a == 0) ? (const void*)(cog + goff)
                                  : (a == 1) ? (const void*)(rmat + goff)
                                             : (const void*)(dmat + goff);
                    async_copy16(g, &tiles[buf * 6144 + a * 2048 + c8 * 256]);
                }
            }
            __syncthreads();
        }
    } else {
        // ================= consumer =================
        const int quad = lane >> 4;
        const int lrow = lane & 15;
        const int row  = wave * 16 + lrow;                       // 0..63 local
        const int g0   = (row * 8 + ((quad * 2)     ^ (row & 7))) * 4;
        const int g1   = (row * 8 + ((quad * 2 + 1) ^ (row & 7))) * 4;
        const __bf16* Tcol = T + (size_t)b * H_ * N_ + (size_t)lrow * N_ + quad * 8;

        f32x4 acc[8];
        #pragma unroll
        for (int i = 0; i < 8; ++i) acc[i] = (f32x4)0.0f;

        __syncthreads();
        for (int s = 0; s < 16; ++s) {
            const int kk = s * 32;
            const int jb = kk + quad * 8;
            // T fragments first: the only vmcnt traffic for this wave
            bf16x8 bf[8];
            #pragma unroll
            for (int nt = 0; nt < 8; ++nt)
                bf[nt] = *(const bf16x8*)(Tcol + (size_t)nt * 16 * N_ + kk);
            // staged tile (lgkm stream, XOR-swizzled: 2-way conflicts = free)
            const int* tb = tiles + (s & 1) * 6144;
            union { int4 v[2]; int   e[8]; } ci, ri;
            union { int4 v[2]; float e[8]; } di;
            ci.v[0] = *(const int4*)(tb + g0);        ci.v[1] = *(const int4*)(tb + g1);
            ri.v[0] = *(const int4*)(tb + 2048 + g0); ri.v[1] = *(const int4*)(tb + 2048 + g1);
            di.v[0] = *(const int4*)(tb + 4096 + g0); di.v[1] = *(const int4*)(tb + 4096 + g1);

            union { bf16x8 v8; __bf16 e[8]; } af;
            #pragma unroll
            for (int q = 0; q < 8; ++q) {
                float val = sdom[ci.e[q] * NRB + ri.e[q]] - di.e[q];
                val = fmaxf(val, 0.0f) * smask[jb + q];
                wmax = fmaxf(wmax, val);
                af.e[q] = (__bf16)val;
            }
            #pragma unroll
            for (int nt = 0; nt < 8; ++nt)
                acc[nt] = __builtin_amdgcn_mfma_f32_16x16x32_bf16(af.v8, bf[nt], acc[nt], 0, 0, 0);
            __syncthreads();
        }

        wmax *= smask[i0 + row];   // fold mask_i (lane's elements are all row `row`)

        // unnormalized output; D layout: col=lane&15, row=quad*4+reg
        const int orow0 = i0 + wave * 16 + quad * 4;
        #pragma unroll
        for (int nt = 0; nt < 8; ++nt) {
            #pragma unroll
            for (int r = 0; r < 4; ++r)
                out[((size_t)b * N_ + orow0 + r) * H_ + nt * 16 + lrow] = acc[nt][r];
        }
    }

    // block max -> one atomic
    #pragma unroll
    for (int off = 32; off > 0; off >>= 1)
        wmax = fmaxf(wmax, __shfl_down(wmax, off));
    if (lane == 0) swmax[wave] = wmax;
    __syncthreads();
    if (t == 0) {
        float m = swmax[0];
        #pragma unroll
        for (int w = 1; w < 8; ++w) m = fmaxf(m, swmax[w]);
        atomicMax(gmax, __float_as_uint(m));   // floats >= 0: uint cmp == float cmp
    }
}

// ---------- scale by m_i / gmax ----------
__global__ __launch_bounds__(256) void k_scale(float* __restrict__ out,
                                               const float* __restrict__ mask,
                                               const unsigned int* __restrict__ gmax) {
    const float inv = 1.0f / __uint_as_float(*gmax);
    const int idx = blockIdx.x * 256 + threadIdx.x;     // 1,048,576 float4s
    const float m = mask[idx >> 5] * inv;               // 32 float4 per (b,i) row
    float4* p = (float4*)out;
    float4 v = p[idx];
    v.x *= m; v.y *= m; v.z *= m; v.w *= m;
    p[idx] = v;
}

extern "C" void kernel_launch(void* const* d_in, const int* in_sizes, int n_in,
                              void* d_out, int out_size, void* d_ws, size_t ws_size,
                              hipStream_t stream) {
    const float* ht     = (const float*)d_in[0];   // (N,B,H) f32
    const int*   rmat   = (const int*)  d_in[1];   // (B,N,N) i32
    const float* dmat   = (const float*)d_in[2];   // (B,N,N) f32
    const float* mask   = (const float*)d_in[3];   // (B,N)   f32
    const int*   cog    = (const int*)  d_in[4];   // (B,N,N) i32
    const float* domain = (const float*)d_in[5];   // (72,72) f32
    float* out = (float*)d_out;

    unsigned int* gmax = (unsigned int*)d_ws;
    __bf16* T = (__bf16*)((char*)d_ws + 256);      // 8 MiB bf16 transpose buffer

    hipMemsetAsync(d_ws, 0, 256, stream);          // gmax = 0.0f
    k_transpose<<<dim3(16, 64), 256, 0, stream>>>(ht, T);
    k_main<<<dim3(512), 512, 0, stream>>>(cog, rmat, dmat, mask, domain, T, out, gmax);
    k_scale<<<4096, 256, 0, stream>>>(out, mask, gmax);
}

// Round 4
// 234.671 us; speedup vs baseline: 1.1475x; 1.0222x over previous
//
#include <hip/hip_runtime.h>

// hardwiredAttention: out[b,i,h] = sum_j w[b,i,j] * h_t[j,b,h]
//   w = m_i*m_j*relu(domain[cog,r]-d) / max(w)
// R4 = R3 (producer/consumer global_load_lds staging) + two fixes:
//  (a) NT cache policy (aux=2) on staged cog/r/d streams so T stays L2-resident
//  (b) consumer double-buffers T fragments one step ahead; the barrier's
//      mandatory vmcnt(0) drain retires the prefetch for free -> no mid-step
//      vmcnt stalls on the consumer critical path.

#define B_   64
#define N_   512
#define H_   128
#define NCOG 72
#define NRB  72

typedef __bf16 bf16x8 __attribute__((ext_vector_type(8)));
typedef float  f32x4  __attribute__((ext_vector_type(4)));

__device__ __forceinline__ void async_copy16_nt(const void* g, void* l) {
    // aux=2 -> NT (non-temporal / evict-first in L2) on gfx940+ cpol encoding
    __builtin_amdgcn_global_load_lds(
        (const __attribute__((address_space(1))) void*)g,
        (__attribute__((address_space(3))) void*)l, 16, 0, 2);
}

// ---------- h_t[j][b][h] fp32 -> T[b][h][j] bf16 ----------
__global__ __launch_bounds__(256) void k_transpose(const float* __restrict__ ht,
                                                   __bf16* __restrict__ T) {
    __shared__ __bf16 tile[32][136];
    const int jt = blockIdx.x * 32;
    const int b  = blockIdx.y;
    const int t  = threadIdx.x;
    {
        const int jj = t >> 3;
        const int h0 = (t & 7) << 4;
        const float* src = ht + ((size_t)(jt + jj) * B_ + b) * H_ + h0;
        float4 v0 = *(const float4*)(src + 0);
        float4 v1 = *(const float4*)(src + 4);
        float4 v2 = *(const float4*)(src + 8);
        float4 v3 = *(const float4*)(src + 12);
        __bf16* dst = &tile[jj][h0];
        dst[0]=(__bf16)v0.x; dst[1]=(__bf16)v0.y; dst[2]=(__bf16)v0.z; dst[3]=(__bf16)v0.w;
        dst[4]=(__bf16)v1.x; dst[5]=(__bf16)v1.y; dst[6]=(__bf16)v1.z; dst[7]=(__bf16)v1.w;
        dst[8]=(__bf16)v2.x; dst[9]=(__bf16)v2.y; dst[10]=(__bf16)v2.z; dst[11]=(__bf16)v2.w;
        dst[12]=(__bf16)v3.x; dst[13]=(__bf16)v3.y; dst[14]=(__bf16)v3.z; dst[15]=(__bf16)v3.w;
    }
    __syncthreads();
    {
        const int h  = t >> 1;
        const int j0 = (t & 1) << 4;
        union { bf16x8 v[2]; __bf16 e[16]; } ob;
        #pragma unroll
        for (int q = 0; q < 16; ++q) ob.e[q] = tile[j0 + q][h];
        __bf16* dst = T + ((size_t)b * H_ + h) * N_ + jt + j0;
        *(bf16x8*)(dst + 0) = ob.v[0];
        *(bf16x8*)(dst + 8) = ob.v[1];
    }
}

// ---------- producer/consumer fused kernel ----------
__global__ __launch_bounds__(512, 4) void k_main(const int* __restrict__ cog,
                                                 const int* __restrict__ rmat,
                                                 const float* __restrict__ dmat,
                                                 const float* __restrict__ mask,
                                                 const float* __restrict__ domain,
                                                 const __bf16* __restrict__ T,
                                                 float* __restrict__ out,
                                                 unsigned int* __restrict__ gmax) {
    __shared__ int   tiles[2 * 3 * 2048];   // [buf][array][64 rows x 32 k] 48 KB
    __shared__ float sdom[NCOG * NRB];      // 20736 B
    __shared__ float smask[N_];             // 2048 B
    __shared__ float swmax[8];

    // XCD swizzle: same-b blocks land on the same XCD (ids differ by 8)
    const int id    = blockIdx.x;
    const int xcd   = id & 7;
    const int i0idx = (id >> 3) & 7;
    const int bhi   = id >> 6;
    const int b     = xcd + 8 * bhi;
    const int i0    = i0idx * 64;

    const int t    = threadIdx.x;
    const int wave = t >> 6;
    const int lane = t & 63;

    for (int k = t; k < NCOG * NRB; k += 512) sdom[k] = domain[k];
    for (int k = t; k < N_; k += 512) smask[k] = mask[b * N_ + k];

    const size_t robase = ((size_t)b * N_ + i0) * N_;   // element offset of tile row 0

    float wmax = 0.0f;

    if (wave >= 4) {
        // ================= producer =================
        const int pw   = wave - 4;                       // 0..3
        const int csw4 = ((lane & 7) ^ (lane >> 3)) * 4; // swizzled chunk (step-invariant)
        const size_t poff = (size_t)(lane >> 3) * N_ + csw4;

        // stage step 0 into buf 0
        #pragma unroll
        for (int q6 = 0; q6 < 6; ++q6) {
            const int q = pw * 6 + q6, a = q >> 3, c8 = q & 7;
            const size_t goff = robase + (size_t)(c8 * 8) * N_ + poff;
            const void* g = (a == 0) ? (const void*)(cog + goff)
                          : (a == 1) ? (const void*)(rmat + goff)
                                     : (const void*)(dmat + goff);
            async_copy16_nt(g, &tiles[a * 2048 + c8 * 256]);
        }
        __syncthreads();
        for (int s = 0; s < 16; ++s) {
            if (s + 1 < 16) {
                const int kk  = (s + 1) * 32;
                const int buf = (s + 1) & 1;
                #pragma unroll
                for (int q6 = 0; q6 < 6; ++q6) {
                    const int q = pw * 6 + q6, a = q >> 3, c8 = q & 7;
                    const size_t goff = robase + (size_t)(c8 * 8) * N_ + kk + poff;
                    const void* g = (a == 0) ? (const void*)(cog + goff)
                                  : (a == 1) ? (const void*)(rmat + goff)
                                             : (const void*)(dmat + goff);
                    async_copy16_nt(g, &tiles[buf * 6144 + a * 2048 + c8 * 256]);
                }
            }
            __syncthreads();
        }
    } else {
        // ================= consumer =================
        const int quad = lane >> 4;
        const int lrow = lane & 15;
        const int row  = wave * 16 + lrow;                       // 0..63 local
        const int g0   = (row * 8 + ((quad * 2)     ^ (row & 7))) * 4;
        const int g1   = (row * 8 + ((quad * 2 + 1) ^ (row & 7))) * 4;
        const __bf16* Tcol = T + (size_t)b * H_ * N_ + (size_t)lrow * N_ + quad * 8;

        f32x4 acc[8];
        #pragma unroll
        for (int i = 0; i < 8; ++i) acc[i] = (f32x4)0.0f;

        // preload step-0 T fragments before the first barrier
        bf16x8 bfbuf[2][8];
        #pragma unroll
        for (int nt = 0; nt < 8; ++nt)
            bfbuf[0][nt] = *(const bf16x8*)(Tcol + (size_t)nt * 16 * N_);

        __syncthreads();
        #pragma unroll 2
        for (int s = 0; s < 16; ++s) {
            const int kk  = s * 32;
            const int cb  = s & 1;
            // (1) prefetch next step's T fragments first; the vmcnt(0) drain at
            //     this step's barrier retires them -> never waited mid-step
            if (s + 1 < 16) {
                #pragma unroll
                for (int nt = 0; nt < 8; ++nt)
                    bfbuf[cb ^ 1][nt] = *(const bf16x8*)(Tcol + (size_t)nt * 16 * N_ + kk + 32);
            }
            // (2) staged tile (lgkm stream, XOR-swizzled)
            const int jb = kk + quad * 8;
            const int* tb = tiles + cb * 6144;
            union { int4 v[2]; int   e[8]; } ci, ri;
            union { int4 v[2]; float e[8]; } di;
            ci.v[0] = *(const int4*)(tb + g0);        ci.v[1] = *(const int4*)(tb + g1);
            ri.v[0] = *(const int4*)(tb + 2048 + g0); ri.v[1] = *(const int4*)(tb + 2048 + g1);
            di.v[0] = *(const int4*)(tb + 4096 + g0); di.v[1] = *(const int4*)(tb + 4096 + g1);

            union { bf16x8 v8; __bf16 e[8]; } af;
            #pragma unroll
            for (int q = 0; q < 8; ++q) {
                float val = sdom[ci.e[q] * NRB + ri.e[q]] - di.e[q];
                val = fmaxf(val, 0.0f) * smask[jb + q];
                wmax = fmaxf(wmax, val);
                af.e[q] = (__bf16)val;
            }
            #pragma unroll
            for (int nt = 0; nt < 8; ++nt)
                acc[nt] = __builtin_amdgcn_mfma_f32_16x16x32_bf16(af.v8, bfbuf[cb][nt], acc[nt], 0, 0, 0);
            __syncthreads();
        }

        wmax *= smask[i0 + row];   // fold mask_i (lane's elements are all row `row`)

        // unnormalized output; D layout: col=lane&15, row=quad*4+reg
        const int orow0 = i0 + wave * 16 + quad * 4;
        #pragma unroll
        for (int nt = 0; nt < 8; ++nt) {
            #pragma unroll
            for (int r = 0; r < 4; ++r)
                out[((size_t)b * N_ + orow0 + r) * H_ + nt * 16 + lrow] = acc[nt][r];
        }
    }

    // block max -> one atomic
    #pragma unroll
    for (int off = 32; off > 0; off >>= 1)
        wmax = fmaxf(wmax, __shfl_down(wmax, off));
    if (lane == 0) swmax[wave] = wmax;
    __syncthreads();
    if (t == 0) {
        float m = swmax[0];
        #pragma unroll
        for (int w = 1; w < 8; ++w) m = fmaxf(m, swmax[w]);
        atomicMax(gmax, __float_as_uint(m));   // floats >= 0: uint cmp == float cmp
    }
}

// ---------- scale by m_i / gmax ----------
__global__ __launch_bounds__(256) void k_scale(float* __restrict__ out,
                                               const float* __restrict__ mask,
                                               const unsigned int* __restrict__ gmax) {
    const float inv = 1.0f / __uint_as_float(*gmax);
    const int idx = blockIdx.x * 256 + threadIdx.x;     // 1,048,576 float4s
    const float m = mask[idx >> 5] * inv;               // 32 float4 per (b,i) row
    float4* p = (float4*)out;
    float4 v = p[idx];
    v.x *= m; v.y *= m; v.z *= m; v.w *= m;
    p[idx] = v;
}

extern "C" void kernel_launch(void* const* d_in, const int* in_sizes, int n_in,
                              void* d_out, int out_size, void* d_ws, size_t ws_size,
                              hipStream_t stream) {
    const float* ht     = (const float*)d_in[0];   // (N,B,H) f32
    const int*   rmat   = (const int*)  d_in[1];   // (B,N,N) i32
    const float* dmat   = (const float*)d_in[2];   // (B,N,N) f32
    const float* mask   = (const float*)d_in[3];   // (B,N)   f32
    const int*   cog    = (const int*)  d_in[4];   // (B,N,N) i32
    const float* domain = (const float*)d_in[5];   // (72,72) f32
    float* out = (float*)d_out;

    unsigned int* gmax = (unsigned int*)d_ws;
    __bf16* T = (__bf16*)((char*)d_ws + 256);      // 8 MiB bf16 transpose buffer

    hipMemsetAsync(d_ws, 0, 256, stream);          // gmax = 0.0f
    k_transpose<<<dim3(16, 64), 256, 0, stream>>>(ht, T);
    k_main<<<dim3(512), 512, 0, stream>>>(cog, rmat, dmat, mask, domain, T, out, gmax);
    k_scale<<<4096, 256, 0, stream>>>(out, mask, gmax);
}

// Round 5
// 232.320 us; speedup vs baseline: 1.1591x; 1.0101x over previous
//
#include <hip/hip_runtime.h>

// hardwiredAttention: out[b,i,h] = sum_j w[b,i,j] * h_t[j,b,h]
//   w = m_i*m_j*relu(domain[cog,r]-d) / max(w)
// R5 = R4 + AITER-style decoupled producer pipeline:
//   4 LDS tile buffers (96 KB), producer issues batch s+3 each step and
//   crosses the barrier with raw asm "s_waitcnt vmcnt(12); s_barrier" so
//   two full batches stay in flight ACROSS barriers (no vmcnt(0) convoy).
//   1 block/CU (LDS 119 KB). Consumers unchanged from R4.

#define B_   64
#define N_   512
#define H_   128
#define NCOG 72
#define NRB  72

typedef __bf16 bf16x8 __attribute__((ext_vector_type(8)));
typedef float  f32x4  __attribute__((ext_vector_type(4)));

__device__ __forceinline__ void async_copy16_nt(const void* g, void* l) {
    // aux=2 -> NT (evict-first in L2)
    __builtin_amdgcn_global_load_lds(
        (const __attribute__((address_space(1))) void*)g,
        (__attribute__((address_space(3))) void*)l, 16, 0, 2);
}

// ---------- h_t[j][b][h] fp32 -> T[b][h][j] bf16 ----------
__global__ __launch_bounds__(256) void k_transpose(const float* __restrict__ ht,
                                                   __bf16* __restrict__ T) {
    __shared__ __bf16 tile[32][136];
    const int jt = blockIdx.x * 32;
    const int b  = blockIdx.y;
    const int t  = threadIdx.x;
    {
        const int jj = t >> 3;
        const int h0 = (t & 7) << 4;
        const float* src = ht + ((size_t)(jt + jj) * B_ + b) * H_ + h0;
        float4 v0 = *(const float4*)(src + 0);
        float4 v1 = *(const float4*)(src + 4);
        float4 v2 = *(const float4*)(src + 8);
        float4 v3 = *(const float4*)(src + 12);
        __bf16* dst = &tile[jj][h0];
        dst[0]=(__bf16)v0.x; dst[1]=(__bf16)v0.y; dst[2]=(__bf16)v0.z; dst[3]=(__bf16)v0.w;
        dst[4]=(__bf16)v1.x; dst[5]=(__bf16)v1.y; dst[6]=(__bf16)v1.z; dst[7]=(__bf16)v1.w;
        dst[8]=(__bf16)v2.x; dst[9]=(__bf16)v2.y; dst[10]=(__bf16)v2.z; dst[11]=(__bf16)v2.w;
        dst[12]=(__bf16)v3.x; dst[13]=(__bf16)v3.y; dst[14]=(__bf16)v3.z; dst[15]=(__bf16)v3.w;
    }
    __syncthreads();
    {
        const int h  = t >> 1;
        const int j0 = (t & 1) << 4;
        union { bf16x8 v[2]; __bf16 e[16]; } ob;
        #pragma unroll
        for (int q = 0; q < 16; ++q) ob.e[q] = tile[j0 + q][h];
        __bf16* dst = T + ((size_t)b * H_ + h) * N_ + jt + j0;
        *(bf16x8*)(dst + 0) = ob.v[0];
        *(bf16x8*)(dst + 8) = ob.v[1];
    }
}

// ---------- producer/consumer fused kernel, 4-deep DMA pipeline ----------
__global__ __launch_bounds__(512, 1) void k_main(const int* __restrict__ cog,
                                                 const int* __restrict__ rmat,
                                                 const float* __restrict__ dmat,
                                                 const float* __restrict__ mask,
                                                 const float* __restrict__ domain,
                                                 const __bf16* __restrict__ T,
                                                 float* __restrict__ out,
                                                 unsigned int* __restrict__ gmax) {
    __shared__ int   tiles[4 * 3 * 2048];   // [buf][array][64 rows x 32 k] 96 KB
    __shared__ float sdom[NCOG * NRB];      // 20736 B
    __shared__ float smask[N_];             // 2048 B
    __shared__ float swmax[8];

    // XCD swizzle: same-b blocks land on the same XCD (ids differ by 8)
    const int id    = blockIdx.x;
    const int xcd   = id & 7;
    const int i0idx = (id >> 3) & 7;
    const int bhi   = id >> 6;
    const int b     = xcd + 8 * bhi;
    const int i0    = i0idx * 64;

    const int t    = threadIdx.x;
    const int wave = t >> 6;
    const int lane = t & 63;

    for (int k = t; k < NCOG * NRB; k += 512) sdom[k] = domain[k];
    for (int k = t; k < N_; k += 512) smask[k] = mask[b * N_ + k];

    const size_t robase = ((size_t)b * N_ + i0) * N_;   // element offset of tile row 0

    float wmax = 0.0f;

    if (wave >= 4) {
        // ================= producer =================
        const int pw   = wave - 4;                       // 0..3
        const int csw4 = ((lane & 7) ^ (lane >> 3)) * 4; // swizzled chunk (step-invariant)
        const size_t poff = (size_t)(lane >> 3) * N_ + csw4;

        #define ISSUE_BATCH(n)                                                      \
            do {                                                                    \
                const int kk_ = (n) * 32, buf_ = (n) & 3;                           \
                _Pragma("unroll")                                                   \
                for (int q6 = 0; q6 < 6; ++q6) {                                    \
                    const int q = pw * 6 + q6, a = q >> 3, c8 = q & 7;              \
                    const size_t goff = robase + (size_t)(c8 * 8) * N_ + kk_ + poff;\
                    const void* g = (a == 0) ? (const void*)(cog + goff)            \
                                  : (a == 1) ? (const void*)(rmat + goff)           \
                                             : (const void*)(dmat + goff);         \
                    async_copy16_nt(g, &tiles[buf_ * 6144 + a * 2048 + c8 * 256]);  \
                }                                                                   \
            } while (0)

        // prologue: 3 batches in flight; publish sdom/smask + batch 0
        ISSUE_BATCH(0);
        ISSUE_BATCH(1);
        ISSUE_BATCH(2);
        asm volatile("s_waitcnt vmcnt(12) lgkmcnt(0)\n\ts_barrier" ::: "memory");

        for (int s = 0; s < 16; ++s) {
            if (s < 13) {
                ISSUE_BATCH(s + 3);
                // batches s+2,s+3 (12 loads) stay in flight across the barrier;
                // in-order retirement => batch s+1 (consumed next step) is done
                asm volatile("s_waitcnt vmcnt(12)\n\ts_barrier" ::: "memory");
            } else if (s == 13) {
                asm volatile("s_waitcnt vmcnt(6)\n\ts_barrier" ::: "memory");
            } else if (s == 14) {
                asm volatile("s_waitcnt vmcnt(0)\n\ts_barrier" ::: "memory");
            } else {
                asm volatile("s_barrier" ::: "memory");
            }
        }
        #undef ISSUE_BATCH
    } else {
        // ================= consumer =================
        const int quad = lane >> 4;
        const int lrow = lane & 15;
        const int row  = wave * 16 + lrow;                       // 0..63 local
        const int g0   = (row * 8 + ((quad * 2)     ^ (row & 7))) * 4;
        const int g1   = (row * 8 + ((quad * 2 + 1) ^ (row & 7))) * 4;
        const __bf16* Tcol = T + (size_t)b * H_ * N_ + (size_t)lrow * N_ + quad * 8;

        f32x4 acc[8];
        #pragma unroll
        for (int i = 0; i < 8; ++i) acc[i] = (f32x4)0.0f;

        // preload step-0 T fragments before the first barrier
        bf16x8 bfbuf[2][8];
        #pragma unroll
        for (int nt = 0; nt < 8; ++nt)
            bfbuf[0][nt] = *(const bf16x8*)(Tcol + (size_t)nt * 16 * N_);

        __syncthreads();
        #pragma unroll 4
        for (int s = 0; s < 16; ++s) {
            const int kk  = s * 32;
            const int cb  = s & 1;
            // prefetch next step's T fragments first (own vmcnt, retired at barrier)
            if (s + 1 < 16) {
                #pragma unroll
                for (int nt = 0; nt < 8; ++nt)
                    bfbuf[cb ^ 1][nt] = *(const bf16x8*)(Tcol + (size_t)nt * 16 * N_ + kk + 32);
            }
            // staged tile (lgkm stream, XOR-swizzled)
            const int jb = kk + quad * 8;
            const int* tb = tiles + (s & 3) * 6144;
            union { int4 v[2]; int   e[8]; } ci, ri;
            union { int4 v[2]; float e[8]; } di;
            ci.v[0] = *(const int4*)(tb + g0);        ci.v[1] = *(const int4*)(tb + g1);
            ri.v[0] = *(const int4*)(tb + 2048 + g0); ri.v[1] = *(const int4*)(tb + 2048 + g1);
            di.v[0] = *(const int4*)(tb + 4096 + g0); di.v[1] = *(const int4*)(tb + 4096 + g1);

            union { bf16x8 v8; __bf16 e[8]; } af;
            #pragma unroll
            for (int q = 0; q < 8; ++q) {
                float val = sdom[ci.e[q] * NRB + ri.e[q]] - di.e[q];
                val = fmaxf(val, 0.0f) * smask[jb + q];
                wmax = fmaxf(wmax, val);
                af.e[q] = (__bf16)val;
            }
            #pragma unroll
            for (int nt = 0; nt < 8; ++nt)
                acc[nt] = __builtin_amdgcn_mfma_f32_16x16x32_bf16(af.v8, bfbuf[cb][nt], acc[nt], 0, 0, 0);
            __syncthreads();
        }

        wmax *= smask[i0 + row];   // fold mask_i (lane's elements are all row `row`)

        // unnormalized output; D layout: col=lane&15, row=quad*4+reg
        const int orow0 = i0 + wave * 16 + quad * 4;
        #pragma unroll
        for (int nt = 0; nt < 8; ++nt) {
            #pragma unroll
            for (int r = 0; r < 4; ++r)
                out[((size_t)b * N_ + orow0 + r) * H_ + nt * 16 + lrow] = acc[nt][r];
        }
    }

    // block max -> one atomic
    #pragma unroll
    for (int off = 32; off > 0; off >>= 1)
        wmax = fmaxf(wmax, __shfl_down(wmax, off));
    if (lane == 0) swmax[wave] = wmax;
    __syncthreads();
    if (t == 0) {
        float m = swmax[0];
        #pragma unroll
        for (int w = 1; w < 8; ++w) m = fmaxf(m, swmax[w]);
        atomicMax(gmax, __float_as_uint(m));   // floats >= 0: uint cmp == float cmp
    }
}

// ---------- scale by m_i / gmax ----------
__global__ __launch_bounds__(256) void k_scale(float* __restrict__ out,
                                               const float* __restrict__ mask,
                                               const unsigned int* __restrict__ gmax) {
    const float inv = 1.0f / __uint_as_float(*gmax);
    const int idx = blockIdx.x * 256 + threadIdx.x;     // 1,048,576 float4s
    const float m = mask[idx >> 5] * inv;               // 32 float4 per (b,i) row
    float4* p = (float4*)out;
    float4 v = p[idx];
    v.x *= m; v.y *= m; v.z *= m; v.w *= m;
    p[idx] = v;
}

extern "C" void kernel_launch(void* const* d_in, const int* in_sizes, int n_in,
                              void* d_out, int out_size, void* d_ws, size_t ws_size,
                              hipStream_t stream) {
    const float* ht     = (const float*)d_in[0];   // (N,B,H) f32
    const int*   rmat   = (const int*)  d_in[1];   // (B,N,N) i32
    const float* dmat   = (const float*)d_in[2];   // (B,N,N) f32
    const float* mask   = (const float*)d_in[3];   // (B,N)   f32
    const int*   cog    = (const int*)  d_in[4];   // (B,N,N) i32
    const float* domain = (const float*)d_in[5];   // (72,72) f32
    float* out = (float*)d_out;

    unsigned int* gmax = (unsigned int*)d_ws;
    __bf16* T = (__bf16*)((char*)d_ws + 256);      // 8 MiB bf16 transpose buffer

    hipMemsetAsync(d_ws, 0, 256, stream);          // gmax = 0.0f
    k_transpose<<<dim3(16, 64), 256, 0, stream>>>(ht, T);
    k_main<<<dim3(512), 512, 0, stream>>>(cog, rmat, dmat, mask, domain, T, out, gmax);
    k_scale<<<4096, 256, 0, stream>>>(out, mask, gmax);
}

// Round 6
// 231.953 us; speedup vs baseline: 1.1610x; 1.0016x over previous
//
#include <hip/hip_runtime.h>

// hardwiredAttention: out[b,i,h] = sum_j w[b,i,j] * h_t[j,b,h]
//   w = m_i*m_j*relu(domain[cog,r]-d) / max(w)
// R6 = R5 + per-block K-phase rotation (kstart = (id&15)*32, wrap mod 512).
// All blocks read rows at stride 2048 B; without rotation every resident
// block hits the same 128 B phase of the 2 KB row simultaneously ->
// HBM-channel / L3-slice hotspot (delivery pinned ~5 B/cyc/CU, linear in
// bytes, depth-insensitive: R3/R4/R5 evidence). Rotation spreads the 256
// resident blocks across all 16 phases. Sum over K is rotation-invariant.

#define B_   64
#define N_   512
#define H_   128
#define NCOG 72
#define NRB  72

typedef __bf16 bf16x8 __attribute__((ext_vector_type(8)));
typedef float  f32x4  __attribute__((ext_vector_type(4)));

__device__ __forceinline__ void async_copy16_nt(const void* g, void* l) {
    // aux=2 -> NT (evict-first in L2)
    __builtin_amdgcn_global_load_lds(
        (const __attribute__((address_space(1))) void*)g,
        (__attribute__((address_space(3))) void*)l, 16, 0, 2);
}

// ---------- h_t[j][b][h] fp32 -> T[b][h][j] bf16 ----------
__global__ __launch_bounds__(256) void k_transpose(const float* __restrict__ ht,
                                                   __bf16* __restrict__ T) {
    __shared__ __bf16 tile[32][136];
    const int jt = blockIdx.x * 32;
    const int b  = blockIdx.y;
    const int t  = threadIdx.x;
    {
        const int jj = t >> 3;
        const int h0 = (t & 7) << 4;
        const float* src = ht + ((size_t)(jt + jj) * B_ + b) * H_ + h0;
        float4 v0 = *(const float4*)(src + 0);
        float4 v1 = *(const float4*)(src + 4);
        float4 v2 = *(const float4*)(src + 8);
        float4 v3 = *(const float4*)(src + 12);
        __bf16* dst = &tile[jj][h0];
        dst[0]=(__bf16)v0.x; dst[1]=(__bf16)v0.y; dst[2]=(__bf16)v0.z; dst[3]=(__bf16)v0.w;
        dst[4]=(__bf16)v1.x; dst[5]=(__bf16)v1.y; dst[6]=(__bf16)v1.z; dst[7]=(__bf16)v1.w;
        dst[8]=(__bf16)v2.x; dst[9]=(__bf16)v2.y; dst[10]=(__bf16)v2.z; dst[11]=(__bf16)v2.w;
        dst[12]=(__bf16)v3.x; dst[13]=(__bf16)v3.y; dst[14]=(__bf16)v3.z; dst[15]=(__bf16)v3.w;
    }
    __syncthreads();
    {
        const int h  = t >> 1;
        const int j0 = (t & 1) << 4;
        union { bf16x8 v[2]; __bf16 e[16]; } ob;
        #pragma unroll
        for (int q = 0; q < 16; ++q) ob.e[q] = tile[j0 + q][h];
        __bf16* dst = T + ((size_t)b * H_ + h) * N_ + jt + j0;
        *(bf16x8*)(dst + 0) = ob.v[0];
        *(bf16x8*)(dst + 8) = ob.v[1];
    }
}

// ---------- producer/consumer fused kernel, 4-deep DMA pipeline ----------
__global__ __launch_bounds__(512, 1) void k_main(const int* __restrict__ cog,
                                                 const int* __restrict__ rmat,
                                                 const float* __restrict__ dmat,
                                                 const float* __restrict__ mask,
                                                 const float* __restrict__ domain,
                                                 const __bf16* __restrict__ T,
                                                 float* __restrict__ out,
                                                 unsigned int* __restrict__ gmax) {
    __shared__ int   tiles[4 * 3 * 2048];   // [buf][array][64 rows x 32 k] 96 KB
    __shared__ float sdom[NCOG * NRB];      // 20736 B
    __shared__ float smask[N_];             // 2048 B
    __shared__ float swmax[8];

    // XCD swizzle: same-b blocks land on the same XCD (ids differ by 8)
    const int id    = blockIdx.x;
    const int xcd   = id & 7;
    const int i0idx = (id >> 3) & 7;
    const int bhi   = id >> 6;
    const int b     = xcd + 8 * bhi;
    const int i0    = i0idx * 64;
    const int kstart = (id & 15) * 32;      // K-phase rotation (channel de-hotspot)

    const int t    = threadIdx.x;
    const int wave = t >> 6;
    const int lane = t & 63;

    for (int k = t; k < NCOG * NRB; k += 512) sdom[k] = domain[k];
    for (int k = t; k < N_; k += 512) smask[k] = mask[b * N_ + k];

    const size_t robase = ((size_t)b * N_ + i0) * N_;   // element offset of tile row 0

    float wmax = 0.0f;

    if (wave >= 4) {
        // ================= producer =================
        const int pw   = wave - 4;                       // 0..3
        const int csw4 = ((lane & 7) ^ (lane >> 3)) * 4; // swizzled chunk (step-invariant)
        const size_t poff = (size_t)(lane >> 3) * N_ + csw4;

        #define ISSUE_BATCH(n)                                                      \
            do {                                                                    \
                const int kk_ = (kstart + (n) * 32) & (N_ - 1);                     \
                const int buf_ = (n) & 3;                                           \
                _Pragma("unroll")                                                   \
                for (int q6 = 0; q6 < 6; ++q6) {                                    \
                    const int q = pw * 6 + q6, a = q >> 3, c8 = q & 7;              \
                    const size_t goff = robase + (size_t)(c8 * 8) * N_ + kk_ + poff;\
                    const void* g = (a == 0) ? (const void*)(cog + goff)            \
                                  : (a == 1) ? (const void*)(rmat + goff)           \
                                             : (const void*)(dmat + goff);         \
                    async_copy16_nt(g, &tiles[buf_ * 6144 + a * 2048 + c8 * 256]);  \
                }                                                                   \
            } while (0)

        // prologue: 3 batches in flight; publish sdom/smask + batch 0
        ISSUE_BATCH(0);
        ISSUE_BATCH(1);
        ISSUE_BATCH(2);
        asm volatile("s_waitcnt vmcnt(12) lgkmcnt(0)\n\ts_barrier" ::: "memory");

        for (int s = 0; s < 16; ++s) {
            if (s < 13) {
                ISSUE_BATCH(s + 3);
                // batches s+2,s+3 (12 loads) stay in flight across the barrier;
                // in-order retirement => batch s+1 (consumed next step) is done
                asm volatile("s_waitcnt vmcnt(12)\n\ts_barrier" ::: "memory");
            } else if (s == 13) {
                asm volatile("s_waitcnt vmcnt(6)\n\ts_barrier" ::: "memory");
            } else if (s == 14) {
                asm volatile("s_waitcnt vmcnt(0)\n\ts_barrier" ::: "memory");
            } else {
                asm volatile("s_barrier" ::: "memory");
            }
        }
        #undef ISSUE_BATCH
    } else {
        // ================= consumer =================
        const int quad = lane >> 4;
        const int lrow = lane & 15;
        const int row  = wave * 16 + lrow;                       // 0..63 local
        const int g0   = (row * 8 + ((quad * 2)     ^ (row & 7))) * 4;
        const int g1   = (row * 8 + ((quad * 2 + 1) ^ (row & 7))) * 4;
        const __bf16* Tcol = T + (size_t)b * H_ * N_ + (size_t)lrow * N_ + quad * 8;

        f32x4 acc[8];
        #pragma unroll
        for (int i = 0; i < 8; ++i) acc[i] = (f32x4)0.0f;

        // preload step-0 T fragments before the first barrier
        bf16x8 bfbuf[2][8];
        #pragma unroll
        for (int nt = 0; nt < 8; ++nt)
            bfbuf[0][nt] = *(const bf16x8*)(Tcol + (size_t)nt * 16 * N_ + kstart);

        __syncthreads();
        #pragma unroll 4
        for (int s = 0; s < 16; ++s) {
            const int kk  = (kstart + s * 32) & (N_ - 1);
            const int cb  = s & 1;
            // prefetch next step's T fragments first (own vmcnt, retired at barrier)
            if (s + 1 < 16) {
                const int kk2 = (kstart + s * 32 + 32) & (N_ - 1);
                #pragma unroll
                for (int nt = 0; nt < 8; ++nt)
                    bfbuf[cb ^ 1][nt] = *(const bf16x8*)(Tcol + (size_t)nt * 16 * N_ + kk2);
            }
            // staged tile (lgkm stream, XOR-swizzled)
            const int jb = kk + quad * 8;
            const int* tb = tiles + (s & 3) * 6144;
            union { int4 v[2]; int   e[8]; } ci, ri;
            union { int4 v[2]; float e[8]; } di;
            ci.v[0] = *(const int4*)(tb + g0);        ci.v[1] = *(const int4*)(tb + g1);
            ri.v[0] = *(const int4*)(tb + 2048 + g0); ri.v[1] = *(const int4*)(tb + 2048 + g1);
            di.v[0] = *(const int4*)(tb + 4096 + g0); di.v[1] = *(const int4*)(tb + 4096 + g1);

            union { bf16x8 v8; __bf16 e[8]; } af;
            #pragma unroll
            for (int q = 0; q < 8; ++q) {
                float val = sdom[ci.e[q] * NRB + ri.e[q]] - di.e[q];
                val = fmaxf(val, 0.0f) * smask[jb + q];
                wmax = fmaxf(wmax, val);
                af.e[q] = (__bf16)val;
            }
            #pragma unroll
            for (int nt = 0; nt < 8; ++nt)
                acc[nt] = __builtin_amdgcn_mfma_f32_16x16x32_bf16(af.v8, bfbuf[cb][nt], acc[nt], 0, 0, 0);
            __syncthreads();
        }

        wmax *= smask[i0 + row];   // fold mask_i (lane's elements are all row `row`)

        // unnormalized output; D layout: col=lane&15, row=quad*4+reg
        const int orow0 = i0 + wave * 16 + quad * 4;
        #pragma unroll
        for (int nt = 0; nt < 8; ++nt) {
            #pragma unroll
            for (int r = 0; r < 4; ++r)
                out[((size_t)b * N_ + orow0 + r) * H_ + nt * 16 + lrow] = acc[nt][r];
        }
    }

    // block max -> one atomic
    #pragma unroll
    for (int off = 32; off > 0; off >>= 1)
        wmax = fmaxf(wmax, __shfl_down(wmax, off));
    if (lane == 0) swmax[wave] = wmax;
    __syncthreads();
    if (t == 0) {
        float m = swmax[0];
        #pragma unroll
        for (int w = 1; w < 8; ++w) m = fmaxf(m, swmax[w]);
        atomicMax(gmax, __float_as_uint(m));   // floats >= 0: uint cmp == float cmp
    }
}

// ---------- scale by m_i / gmax ----------
__global__ __launch_bounds__(256) void k_scale(float* __restrict__ out,
                                               const float* __restrict__ mask,
                                               const unsigned int* __restrict__ gmax) {
    const float inv = 1.0f / __uint_as_float(*gmax);
    const int idx = blockIdx.x * 256 + threadIdx.x;     // 1,048,576 float4s
    const float m = mask[idx >> 5] * inv;               // 32 float4 per (b,i) row
    float4* p = (float4*)out;
    float4 v = p[idx];
    v.x *= m; v.y *= m; v.z *= m; v.w *= m;
    p[idx] = v;
}

extern "C" void kernel_launch(void* const* d_in, const int* in_sizes, int n_in,
                              void* d_out, int out_size, void* d_ws, size_t ws_size,
                              hipStream_t stream) {
    const float* ht     = (const float*)d_in[0];   // (N,B,H) f32
    const int*   rmat   = (const int*)  d_in[1];   // (B,N,N) i32
    const float* dmat   = (const float*)d_in[2];   // (B,N,N) f32
    const float* mask   = (const float*)d_in[3];   // (B,N)   f32
    const int*   cog    = (const int*)  d_in[4];   // (B,N,N) i32
    const float* domain = (const float*)d_in[5];   // (72,72) f32
    float* out = (float*)d_out;

    unsigned int* gmax = (unsigned int*)d_ws;
    __bf16* T = (__bf16*)((char*)d_ws + 256);      // 8 MiB bf16 transpose buffer

    hipMemsetAsync(d_ws, 0, 256, stream);          // gmax = 0.0f
    k_transpose<<<dim3(16, 64), 256, 0, stream>>>(ht, T);
    k_main<<<dim3(512), 512, 0, stream>>>(cog, rmat, dmat, mask, domain, T, out, gmax);
    k_scale<<<4096, 256, 0, stream>>>(out, mask, gmax);
}